// Round 1
// baseline (16717.982 us; speedup 1.0000x reference)
//
#include <hip/hip_runtime.h>
#include <math.h>

#define NBATCH 262144
#define ROWS   64
#define HST    132            // hbuf/tbuf row stride (floats), 16B-aligned rows
#define INVSQH 0.08838834764831845f   // 1/sqrt(128)

__device__ __forceinline__ float softplusf(float x) {
    return (x > 15.f) ? x : log1pf(__expf(x));
}

// Rational-quadratic spline inverse for one scalar. p[0..7]=uw_raw, p[8..15]=uh_raw,
// p[16..22]=ud (uw/uh get divided by sqrt(H), ud is raw — matches reference).
__device__ __forceinline__ void rqs_inv(float y, const float* __restrict__ p,
                                        float& xout, float& ldout)
{
    float uw[8], uh[8];
#pragma unroll
    for (int j = 0; j < 8; ++j) uw[j] = p[j] * INVSQH;
#pragma unroll
    for (int j = 0; j < 8; ++j) uh[j] = p[8 + j] * INVSQH;
    float mw = uw[0], mh = uh[0];
#pragma unroll
    for (int j = 1; j < 8; ++j) { mw = fmaxf(mw, uw[j]); mh = fmaxf(mh, uh[j]); }
    float ew[8], eh[8], sw = 0.f, sh = 0.f;
#pragma unroll
    for (int j = 0; j < 8; ++j) {
        ew[j] = __expf(uw[j] - mw); sw += ew[j];
        eh[j] = __expf(uh[j] - mh); sh += eh[j];
    }
    float isw = 0.992f / sw, ish = 0.992f / sh;   // 0.992 = 1 - MINW*NB
    float cw[9], ch[9];
    cw[0] = -3.f; ch[0] = -3.f;
    float aw = 0.f, ah = 0.f;
#pragma unroll
    for (int j = 0; j < 8; ++j) {
        aw += 0.001f + ew[j] * isw;
        ah += 0.001f + eh[j] * ish;
        cw[j + 1] = 6.f * aw - 3.f;
        ch[j + 1] = 6.f * ah - 3.f;
    }
    cw[8] = 3.f; ch[8] = 3.f;
    float d[9];
    d[0] = 1.f; d[8] = 1.f;   // MIND + softplus(DCONST) == 1 exactly
#pragma unroll
    for (int j = 0; j < 7; ++j) d[j + 1] = 0.001f + softplusf(p[16 + j]);

    float yc = fminf(fmaxf(y, -3.f), 3.f);
    float yk = ch[0], hk = ch[1] - ch[0], xk = cw[0], wk = cw[1] - cw[0];
    float dk = d[0], dk1 = d[1];
#pragma unroll
    for (int j = 1; j < 8; ++j) {
        bool cge = (yc >= ch[j]);
        yk  = cge ? ch[j] : yk;
        hk  = cge ? (ch[j + 1] - ch[j]) : hk;
        xk  = cge ? cw[j] : xk;
        wk  = cge ? (cw[j + 1] - cw[j]) : wk;
        dk  = cge ? d[j] : dk;
        dk1 = cge ? d[j + 1] : dk1;
    }
    float sk = hk / wk;
    float dy = yc - yk;
    float t2 = dk + dk1 - 2.f * sk;
    float av = dy * t2 + hk * (sk - dk);
    float bv = hk * dk - dy * t2;
    float cv = -sk * dy;
    float disc = fmaxf(bv * bv - 4.f * av * cv, 0.f);
    float theta = 2.f * cv / (-bv - sqrtf(disc));
    float xo = fmaf(theta, wk, xk);
    float om = 1.f - theta;
    float denom = fmaf(t2, theta * om, sk);
    float dnum = sk * sk * (dk1 * theta * theta + 2.f * sk * theta * om + dk * om * om);
    float ldf = __logf(dnum) - 2.f * __logf(denom);
    bool inside = (y >= -3.f) && (y <= 3.f);
    xout  = inside ? xo : y;
    ldout = inside ? -ldf : 0.f;
}

// Load one 128x128 fp32 weight matrix (row-major [o][k]) into LDS, float4-swizzled:
// slot(o,k4) = o*32 + (k4 ^ ((o>>3)&7)). Spreads inner-loop reads across bank groups.
__device__ __forceinline__ void load_wtile(const float* __restrict__ Wg, float4* wt4, int tid)
{
    const float4* Wg4 = (const float4*)Wg;
#pragma unroll
    for (int it = 0; it < 16; ++it) {
        int f = it * 256 + tid;
        int o = f >> 5, k4 = f & 31;
        wt4[o * 32 + (k4 ^ ((o >> 3) & 7))] = Wg4[f];
    }
}

// C[r][o] = sum_k relu(src[r][k]) * W[o][k] + bias[o];  ACCUM: dst += else dst =.
// Thread tile: 4 rows x 8 cols (tx=tid&15 -> o0=8*tx, ty=tid>>4 -> r0=4*ty).
template <int ACCUM>
__device__ __forceinline__ void matvec(const float* __restrict__ src, float* __restrict__ dst,
                                       const float4* __restrict__ wt4,
                                       const float* __restrict__ bias, int tx, int ty)
{
    float acc[4][8];
#pragma unroll
    for (int i = 0; i < 4; ++i)
#pragma unroll
        for (int j = 0; j < 8; ++j) acc[i][j] = 0.f;
    const int r0 = ty * 4, o0 = tx * 8, swz = tx & 7;
#pragma unroll 4
    for (int k4 = 0; k4 < 32; ++k4) {
        float4 avv[4];
#pragma unroll
        for (int i = 0; i < 4; ++i) avv[i] = *(const float4*)&src[(r0 + i) * HST + k4 * 4];
#pragma unroll
        for (int i = 0; i < 4; ++i) {
            avv[i].x = fmaxf(avv[i].x, 0.f); avv[i].y = fmaxf(avv[i].y, 0.f);
            avv[i].z = fmaxf(avv[i].z, 0.f); avv[i].w = fmaxf(avv[i].w, 0.f);
        }
#pragma unroll
        for (int j = 0; j < 8; ++j) {
            float4 wv = wt4[(o0 + j) * 32 + (k4 ^ swz)];
#pragma unroll
            for (int i = 0; i < 4; ++i) {
                acc[i][j] = fmaf(avv[i].x, wv.x, acc[i][j]);
                acc[i][j] = fmaf(avv[i].y, wv.y, acc[i][j]);
                acc[i][j] = fmaf(avv[i].z, wv.z, acc[i][j]);
                acc[i][j] = fmaf(avv[i].w, wv.w, acc[i][j]);
            }
        }
    }
#pragma unroll
    for (int i = 0; i < 4; ++i) {
#pragma unroll
        for (int j = 0; j < 8; ++j) {
            float v = acc[i][j] + bias[o0 + j];
            if (ACCUM) dst[(r0 + i) * HST + o0 + j] += v;
            else       dst[(r0 + i) * HST + o0 + j] = v;
        }
    }
}

extern "C" __global__ __launch_bounds__(256, 1)
void nsf_kernel(const float* __restrict__ z0g, const float* __restrict__ xg,
                const float* __restrict__ sgg,
                const float* __restrict__ n1w1, const float* __restrict__ n1b1,
                const float* __restrict__ n1w2, const float* __restrict__ n1b2,
                const float* __restrict__ n2w1, const float* __restrict__ n2b1,
                const float* __restrict__ n2w2, const float* __restrict__ n2b2,
                const float* __restrict__ W0g,  const float* __restrict__ b0g,
                const float* __restrict__ Wresg,const float* __restrict__ bresg,
                const float* __restrict__ Wfg,  const float* __restrict__ bfg,
                const float* __restrict__ lulg, const float* __restrict__ luug,
                const float* __restrict__ ludg, const float* __restrict__ lubg,
                const int* __restrict__ permsg, float* __restrict__ outg)
{
    __shared__ float  hbuf[ROWS * HST];
    __shared__ float  tbuf[ROWS * HST];
    __shared__ float4 wt4[128 * 32];
    __shared__ float  p1sh[ROWS * 24];
    __shared__ float  out0sh[ROWS];

    const int tid = threadIdx.x;
    const int tx = tid & 15, ty = tid >> 4;
    const int sbase = blockIdx.x * ROWS;

    float zz0 = 0.f, zz1 = 0.f, ld = 0.f;

    // ---- conditioning MLPs (sample-owner lanes 0..63) ----
    if (tid < ROWS) {
        int s = sbase + tid;
        float za = z0g[2 * s], zb = z0g[2 * s + 1];
        float xa = xg[2 * s],  xb = xg[2 * s + 1];
        float sg = sgg[s];
        float t0 = n1b2[0], t1 = n1b2[1];
#pragma unroll
        for (int m = 0; m < 32; ++m) {
            float hm = fmaf(sg, n1w1[m], n1b1[m]);
            hm = hm / (1.f + __expf(-hm));           // silu
            t0 = fmaf(hm, n1w2[m], t0);
            t1 = fmaf(hm, n1w2[32 + m], t1);
        }
        float u0 = n2b2[0], u1 = n2b2[1];
#pragma unroll
        for (int m = 0; m < 32; ++m) {
            float hm = za * n2w1[4 * m] + zb * n2w1[4 * m + 1]
                     + xa * n2w1[4 * m + 2] + xb * n2w1[4 * m + 3] + n2b1[m];
            hm = hm / (1.f + __expf(-hm));
            u0 = fmaf(hm, n2w2[m], u0);
            u1 = fmaf(hm, n2w2[32 + m], u1);
        }
        zz0 = u0 + t0; zz1 = u1 + t1;
    }

    for (int L = 0; L < 16; ++L) {
        float y0 = zz0, y1 = zz1, out0 = 0.f, ldp0 = 0.f;
        if (tid < ROWS) {
            // dim-0 spline: params are per-layer constants bf[L][0..22]
            rqs_inv(y0, &bfg[L * 46], out0, ldp0);
            out0sh[tid] = out0;
        }
        __syncthreads();

        // ---- h init: h[r][k] = out0[r]*W0[L][k][0] + b0[L][k] ----
        {
            int kk = tid & 127, g = tid >> 7;
            float w0k = W0g[L * 256 + 2 * kk];
            float b0k = b0g[L * 128 + kk];
#pragma unroll 8
            for (int r = g * 32; r < g * 32 + 32; ++r)
                hbuf[r * HST + kk] = fmaf(out0sh[r], w0k, b0k);
        }

        const float* Wbase = Wresg + L * 4 * 16384;
        const float* bbase = bresg + L * 4 * 128;
#pragma unroll 1
        for (int blk = 0; blk < 2; ++blk) {
            __syncthreads();
            load_wtile(Wbase + (2 * blk) * 16384, wt4, tid);
            __syncthreads();
            matvec<0>(hbuf, tbuf, wt4, bbase + (2 * blk) * 128, tx, ty);
            __syncthreads();
            load_wtile(Wbase + (2 * blk + 1) * 16384, wt4, tid);
            __syncthreads();
            matvec<1>(tbuf, hbuf, wt4, bbase + (2 * blk + 1) * 128, tx, ty);
        }
        __syncthreads();

        // ---- final projection: p1[o] = h . Wf[L][23+o][:] + bf[L][23+o], o in [0,23) ----
        {
            int r = tid & 63, og = tid >> 6;
            int ob = og * 6;
            int on = (og < 3) ? 6 : 5;
            const float4* hr = (const float4*)&hbuf[r * HST];
            for (int oo = 0; oo < on; ++oo) {
                const float4* wfr = (const float4*)&Wfg[(L * 46 + 23 + ob + oo) * 128];
                float s0 = 0.f, s1 = 0.f, s2 = 0.f, s3 = 0.f;
#pragma unroll 8
                for (int k4 = 0; k4 < 32; ++k4) {
                    float4 hv = hr[k4];
                    float4 wv = wfr[k4];
                    s0 = fmaf(hv.x, wv.x, s0); s1 = fmaf(hv.y, wv.y, s1);
                    s2 = fmaf(hv.z, wv.z, s2); s3 = fmaf(hv.w, wv.w, s3);
                }
                p1sh[r * 24 + ob + oo] = (s0 + s1) + (s2 + s3) + bfg[L * 46 + 23 + ob + oo];
            }
        }
        __syncthreads();

        if (tid < ROWS) {
            float pp[23];
#pragma unroll
            for (int j = 0; j < 23; ++j) pp[j] = p1sh[tid * 24 + j];
            float out1, ldp1;
            rqs_inv(y1, pp, out1, ldp1);
            ld += ldp0 + ldp1;

            // ---- LU-coupling inverse + permutation ----
            float dg0 = softplusf(ludg[2 * L])     + 0.001f;
            float dg1 = softplusf(ludg[2 * L + 1]) + 0.001f;
            float ll = lulg[L], uu = luug[L];
            float v0 = out0 - lubg[2 * L];
            float v1 = out1 - lubg[2 * L + 1];
            float idet = 1.f / (dg0 * dg1);
            float zn0 = (v0 * (ll * uu + dg1) - v1 * uu) * idet;
            float zn1 = (v1 - v0 * ll) * dg0 * idet;
            ld -= __logf(dg0) + __logf(dg1);
            int pa = permsg[2 * L], pb = permsg[2 * L + 1];
            zz0 = pa ? zn1 : zn0;
            zz1 = pb ? zn1 : zn0;
        }
        // next iteration's first __syncthreads() covers the out0sh / hbuf hazards
    }

    if (tid < ROWS) {
        int s = sbase + tid;
        outg[2 * s]     = zz0;
        outg[2 * s + 1] = zz1;
        outg[2 * NBATCH + s] = ld;
    }
}

extern "C" void kernel_launch(void* const* d_in, const int* in_sizes, int n_in,
                              void* d_out, int out_size, void* d_ws, size_t ws_size,
                              hipStream_t stream)
{
    const float* z0g  = (const float*)d_in[0];
    const float* xg   = (const float*)d_in[1];
    const float* sgg  = (const float*)d_in[2];
    const float* n1w1 = (const float*)d_in[3];
    const float* n1b1 = (const float*)d_in[4];
    const float* n1w2 = (const float*)d_in[5];
    const float* n1b2 = (const float*)d_in[6];
    const float* n2w1 = (const float*)d_in[7];
    const float* n2b1 = (const float*)d_in[8];
    const float* n2w2 = (const float*)d_in[9];
    const float* n2b2 = (const float*)d_in[10];
    const float* W0g  = (const float*)d_in[11];
    const float* b0g  = (const float*)d_in[12];
    const float* Wres = (const float*)d_in[13];
    const float* bres = (const float*)d_in[14];
    const float* Wfg  = (const float*)d_in[15];
    const float* bfg  = (const float*)d_in[16];
    const float* lul  = (const float*)d_in[17];
    const float* luu  = (const float*)d_in[18];
    const float* lud  = (const float*)d_in[19];
    const float* lub  = (const float*)d_in[20];
    const int*   perms= (const int*)d_in[21];
    float* outg = (float*)d_out;

    dim3 grid(NBATCH / ROWS), block(256);
    nsf_kernel<<<grid, block, 0, stream>>>(z0g, xg, sgg,
                                           n1w1, n1b1, n1w2, n1b2,
                                           n2w1, n2b1, n2w2, n2b2,
                                           W0g, b0g, Wres, bres, Wfg, bfg,
                                           lul, luu, lud, lub, perms, outg);
}

// Round 2
// 1687.291 us; speedup vs baseline: 9.9082x; 9.9082x over previous
//
#include <hip/hip_runtime.h>
#include <math.h>

#define NBATCH 262144
#define INVSQH 0.08838834764831845f   // 1/sqrt(128)

typedef float f32x4 __attribute__((ext_vector_type(4)));
typedef short s16x8 __attribute__((ext_vector_type(8)));

// ---- workspace layout (bytes) ----
#define WSR_OFF  0                 // Wres bf16, swizzled: 64 stages * 32768 B
#define WSF_OFF  2097152           // Wf padded [32][128] bf16 swizzled: 16 * 8192 B
#define REC_OFF  2228224           // 16 * 40 floats (cw9 ch9 d9 lu4 lub2)
#define LDC_OFF  2230784           // 1 float: sum over layers of log(dg0)+log(dg1)

// ---- LDS layout (bytes) ----
#define A0_OFF   0                 // 64 x 256B  activations bf16 (swizzled chunks)
#define A1_OFF   16384
#define BM_OFF   32768             // 128 x 256B weights bf16 (swizzled)
#define BP_OFF   65536             // 32 x 256B  proj weights
#define OUT0_OFF 73728             // 64 floats
#define SMEM_BYTES 73984
#define P1_STRIDE 36               // floats; p1sh overlays A1

__device__ __forceinline__ float softplusf(float x) {
    return (x > 15.f) ? x : log1pf(__expf(x));
}
__device__ __forceinline__ unsigned short f2bf(float x) {
    unsigned u = __float_as_uint(x);
    unsigned r = (u + 0x7FFFu + ((u >> 16) & 1u)) >> 16;
    return (unsigned short)r;
}

// shared quadratic-solve tail of the RQS inverse
__device__ __forceinline__ void rqs_solve(float y, float yc, float yk, float hk, float xk,
                                          float wk, float dk, float dk1,
                                          float& xout, float& ldout)
{
    float sk = hk / wk;
    float dy = yc - yk;
    float t2 = dk + dk1 - 2.f * sk;
    float av = dy * t2 + hk * (sk - dk);
    float bv = hk * dk - dy * t2;
    float cv = -sk * dy;
    float disc = fmaxf(bv * bv - 4.f * av * cv, 0.f);
    float theta = 2.f * cv / (-bv - sqrtf(disc));
    float xo = fmaf(theta, wk, xk);
    float om = 1.f - theta;
    float denom = fmaf(t2, theta * om, sk);
    float dnum = sk * sk * (dk1 * theta * theta + 2.f * sk * theta * om + dk * om * om);
    float ldf = __logf(dnum) - 2.f * __logf(denom);
    bool inside = (y >= -3.f) && (y <= 3.f);
    xout  = inside ? xo : y;
    ldout = inside ? -ldf : 0.f;
}

// full RQS inverse from raw params p[0..22] (dim-1, per-sample params)
__device__ __forceinline__ void rqs_inv(float y, const float* __restrict__ p,
                                        float& xout, float& ldout)
{
    float uw[8], uh[8];
#pragma unroll
    for (int j = 0; j < 8; ++j) uw[j] = p[j] * INVSQH;
#pragma unroll
    for (int j = 0; j < 8; ++j) uh[j] = p[8 + j] * INVSQH;
    float mw = uw[0], mh = uh[0];
#pragma unroll
    for (int j = 1; j < 8; ++j) { mw = fmaxf(mw, uw[j]); mh = fmaxf(mh, uh[j]); }
    float ew[8], eh[8], sw = 0.f, sh = 0.f;
#pragma unroll
    for (int j = 0; j < 8; ++j) {
        ew[j] = __expf(uw[j] - mw); sw += ew[j];
        eh[j] = __expf(uh[j] - mh); sh += eh[j];
    }
    float isw = 0.992f / sw, ish = 0.992f / sh;
    float cw[9], ch[9];
    cw[0] = -3.f; ch[0] = -3.f;
    float aw = 0.f, ah = 0.f;
#pragma unroll
    for (int j = 0; j < 8; ++j) {
        aw += 0.001f + ew[j] * isw;
        ah += 0.001f + eh[j] * ish;
        cw[j + 1] = 6.f * aw - 3.f;
        ch[j + 1] = 6.f * ah - 3.f;
    }
    cw[8] = 3.f; ch[8] = 3.f;
    float d[9];
    d[0] = 1.f; d[8] = 1.f;
#pragma unroll
    for (int j = 0; j < 7; ++j) d[j + 1] = 0.001f + softplusf(p[16 + j]);

    float yc = fminf(fmaxf(y, -3.f), 3.f);
    float yk = ch[0], hk = ch[1] - ch[0], xk = cw[0], wk = cw[1] - cw[0];
    float dk = d[0], dk1 = d[1];
#pragma unroll
    for (int j = 1; j < 8; ++j) {
        bool cge = (yc >= ch[j]);
        yk  = cge ? ch[j] : yk;
        hk  = cge ? (ch[j + 1] - ch[j]) : hk;
        xk  = cge ? cw[j] : xk;
        wk  = cge ? (cw[j + 1] - cw[j]) : wk;
        dk  = cge ? d[j] : dk;
        dk1 = cge ? d[j + 1] : dk1;
    }
    rqs_solve(y, yc, yk, hk, xk, wk, dk, dk1, xout, ldout);
}

// RQS inverse from precomputed knots rec = {cw[9], ch[9], d[9]} (dim-0, per-layer const)
__device__ __forceinline__ void rqs_knots(float y, const float* __restrict__ rec,
                                          float& xout, float& ldout)
{
    const float* cw = rec;
    const float* ch = rec + 9;
    const float* dd = rec + 18;
    float yc = fminf(fmaxf(y, -3.f), 3.f);
    float yk = ch[0], hk = ch[1] - ch[0], xk = cw[0], wk = cw[1] - cw[0];
    float dk = dd[0], dk1 = dd[1];
#pragma unroll
    for (int j = 1; j < 8; ++j) {
        bool cge = (yc >= ch[j]);
        yk  = cge ? ch[j] : yk;
        hk  = cge ? (ch[j + 1] - ch[j]) : hk;
        xk  = cge ? cw[j] : xk;
        wk  = cge ? (cw[j + 1] - cw[j]) : wk;
        dk  = cge ? dd[j] : dk;
        dk1 = cge ? dd[j + 1] : dk1;
    }
    rqs_solve(y, yc, yk, hk, xk, wk, dk, dk1, xout, ldout);
}

// async global->LDS, 16B per lane; wave w stages its quarter of nbytes
__device__ __forceinline__ void prefetch_lds(const char* src, char* dst, int nbytes,
                                             int w, int lane)
{
    int slice = nbytes >> 2;
    const char* s = src + w * slice + lane * 16;
    char* d = dst + w * slice;
    for (int i = 0; i < slice; i += 1024)
        __builtin_amdgcn_global_load_lds(
            (const __attribute__((address_space(1))) unsigned int*)(s + i),
            (__attribute__((address_space(3))) unsigned int*)(d + i), 16, 0, 0);
}

// write C-layout f32 values as bf16 into swizzled A buffer.
// element (m,k) lives at byte m*256 + ((k>>3)^(m&7))*16 + (k&7)*2
template <int RELU>
__device__ __forceinline__ void write_A(char* Aout, const f32x4 v[2][4], int w, int q, int tx)
{
    int tx7 = tx & 7;
    int kb = (w << 2) + (tx >> 3);
#pragma unroll
    for (int ct = 0; ct < 2; ++ct) {
        int kc = kb + (ct << 1);
#pragma unroll
        for (int rt = 0; rt < 4; ++rt)
#pragma unroll
            for (int reg = 0; reg < 4; ++reg) {
                int m = (rt << 4) + (q << 2) + reg;
                int s = ((q << 2) + reg) & 7;
                float x = v[ct][rt][reg];
                if (RELU) x = fmaxf(x, 0.f);
                *(unsigned short*)(Aout + m * 256 + ((kc ^ s) << 4) + (tx7 << 1)) = f2bf(x);
            }
    }
}

// one 64x128x128 MFMA stage. Wave w: all 4 row-tiles x col-tiles {2w,2w+1}.
// HSTAGE: h += acc+bias, write h; else write acc+bias. RELUOUT: relu before write.
template <int HSTAGE, int RELUOUT>
__device__ __forceinline__ void res_stage(const char* Ain, char* Aout, const char* Bm,
                                          const float* biasg, f32x4 h[2][4],
                                          const char* pf1s, char* pf1d, int pf1n,
                                          const char* pf2s, char* pf2d, int pf2n,
                                          int w, int q, int tx, int lane)
{
    int tx7 = tx & 7;
    f32x4 zero = {0.f, 0.f, 0.f, 0.f};
    f32x4 acc[2][4];
#pragma unroll
    for (int ct = 0; ct < 2; ++ct)
#pragma unroll
        for (int rt = 0; rt < 4; ++rt) acc[ct][rt] = zero;

#pragma unroll
    for (int kt = 0; kt < 4; ++kt) {
        int cc = ((kt << 2) + q) ^ tx7;
        s16x8 a[4], b[2];
#pragma unroll
        for (int rt = 0; rt < 4; ++rt)
            a[rt] = *(const s16x8*)(Ain + (((rt << 4) + tx) << 8) + (cc << 4));
#pragma unroll
        for (int ct = 0; ct < 2; ++ct)
            b[ct] = *(const s16x8*)(Bm + (((w << 5) + (ct << 4) + tx) << 8) + (cc << 4));
#pragma unroll
        for (int ct = 0; ct < 2; ++ct)
#pragma unroll
            for (int rt = 0; rt < 4; ++rt)
                acc[ct][rt] = __builtin_amdgcn_mfma_f32_16x16x32_bf16(a[rt], b[ct], acc[ct][rt], 0, 0, 0);
    }

    // prefetch next-stage weights into this wave's private B slice
    if (pf1n) prefetch_lds(pf1s, pf1d, pf1n, w, lane);
    if (pf2n) prefetch_lds(pf2s, pf2d, pf2n, w, lane);

    f32x4 outv[2][4];
#pragma unroll
    for (int ct = 0; ct < 2; ++ct) {
        float bb = biasg[(w << 5) + (ct << 4) + tx];
#pragma unroll
        for (int rt = 0; rt < 4; ++rt) {
            f32x4 v = acc[ct][rt] + bb;
            if (HSTAGE) { h[ct][rt] = h[ct][rt] + v; outv[ct][rt] = h[ct][rt]; }
            else outv[ct][rt] = v;
        }
    }
    write_A<RELUOUT>(Aout, outv, w, q, tx);
}

// ---------------- prep kernel: bf16 weight images + per-layer constants ----------------
extern "C" __global__ void nsf_prep(const float* __restrict__ Wresg, const float* __restrict__ Wfg,
                                    const float* __restrict__ bfg,
                                    const float* __restrict__ lulg, const float* __restrict__ luug,
                                    const float* __restrict__ ludg, const float* __restrict__ lubg,
                                    const int* __restrict__ permsg, char* __restrict__ ws)
{
    int t = blockIdx.x * blockDim.x + threadIdx.x;
    int stride = gridDim.x * blockDim.x;
    unsigned short* wr = (unsigned short*)(ws + WSR_OFF);
    unsigned short* wf = (unsigned short*)(ws + WSF_OFF);

    // Wres: stage sidx = L*4 + blk*2 + sub (matches source linear order)
    for (int e = t; e < 16 * 4 * 16384; e += stride) {
        int sidx = e >> 14;
        int rem = e & 16383;
        int o = rem >> 7, k = rem & 127;
        unsigned short v = f2bf(Wresg[e]);
        wr[sidx * 16384 + o * 128 + (((k >> 3) ^ (o & 7)) << 3) + (k & 7)] = v;
    }
    // Wf padded to 32 rows (rows 23..31 zero), per layer
    for (int e = t; e < 16 * 32 * 128; e += stride) {
        int L = e >> 12;
        int rem = e & 4095;
        int o = rem >> 7, k = rem & 127;
        float x = (o < 23) ? Wfg[(L * 46 + 23 + o) * 128 + k] : 0.f;
        wf[L * 4096 + o * 128 + (((k >> 3) ^ (o & 7)) << 3) + (k & 7)] = f2bf(x);
    }
    // per-layer: dim0 spline knots + LU(+perm) matrix
    if (t < 16) {
        int L = t;
        float* rec = (float*)(ws + REC_OFF) + L * 40;
        const float* p = bfg + L * 46;
        for (int half = 0; half < 2; ++half) {
            float u[8], m = -1e30f;
            for (int j = 0; j < 8; ++j) { u[j] = p[half * 8 + j] * INVSQH; m = fmaxf(m, u[j]); }
            float e[8], s = 0.f;
            for (int j = 0; j < 8; ++j) { e[j] = expf(u[j] - m); s += e[j]; }
            float cum = 0.f;
            rec[half * 9 + 0] = -3.f;
            for (int j = 0; j < 8; ++j) {
                cum += 0.001f + 0.992f * e[j] / s;
                rec[half * 9 + 1 + j] = 6.f * cum - 3.f;
            }
            rec[half * 9 + 8] = 3.f;
        }
        rec[18] = 1.f; rec[26] = 1.f;
        for (int j = 0; j < 7; ++j) {
            float x = p[16 + j];
            rec[19 + j] = 0.001f + ((x > 15.f) ? x : log1pf(expf(x)));
        }
        float x0 = ludg[2 * L], x1 = ludg[2 * L + 1];
        float dg0 = 0.001f + ((x0 > 15.f) ? x0 : log1pf(expf(x0)));
        float dg1 = 0.001f + ((x1 > 15.f) ? x1 : log1pf(expf(x1)));
        float ll = lulg[L], uu = luug[L];
        float det = dg0 * dg1;
        float c00 = (ll * uu + dg1) / det, c01 = -uu / det;
        float c10 = -ll / dg1, c11 = 1.f / dg1;
        int pa = permsg[2 * L], pb = permsg[2 * L + 1];
        rec[27] = pa ? c10 : c00; rec[28] = pa ? c11 : c01;
        rec[29] = pb ? c10 : c00; rec[30] = pb ? c11 : c01;
        rec[31] = lubg[2 * L];    rec[32] = lubg[2 * L + 1];
    }
    if (t == 16) {
        float s = 0.f;
        for (int L = 0; L < 16; ++L) {
            float x0 = ludg[2 * L], x1 = ludg[2 * L + 1];
            float dg0 = 0.001f + ((x0 > 15.f) ? x0 : log1pf(expf(x0)));
            float dg1 = 0.001f + ((x1 > 15.f) ? x1 : log1pf(expf(x1)));
            s += logf(dg0) + logf(dg1);
        }
        *(float*)(ws + LDC_OFF) = s;
    }
}

// ---------------- main fused kernel ----------------
extern "C" __global__ __launch_bounds__(256, 2)
void nsf_kernel(const float* __restrict__ z0g, const float* __restrict__ xg,
                const float* __restrict__ sgg,
                const float* __restrict__ n1w1, const float* __restrict__ n1b1,
                const float* __restrict__ n1w2, const float* __restrict__ n1b2,
                const float* __restrict__ n2w1, const float* __restrict__ n2b1,
                const float* __restrict__ n2w2, const float* __restrict__ n2b2,
                const float* __restrict__ W0g,  const float* __restrict__ b0g,
                const float* __restrict__ bresg, const float* __restrict__ bfg,
                const char* __restrict__ ws, float* __restrict__ outg)
{
    extern __shared__ char smem[];
    char* A0 = smem + A0_OFF;
    char* A1 = smem + A1_OFF;
    char* BM = smem + BM_OFF;
    char* BP = smem + BP_OFF;
    float* out0sh = (float*)(smem + OUT0_OFF);
    float* p1sh = (float*)(smem + A1_OFF);   // overlay: A1 is dead during projection

    const int tid = threadIdx.x;
    const int lane = tid & 63, w = tid >> 6;
    const int q = lane >> 4, tx = lane & 15, tx7 = tx & 7;
    const int sbase = blockIdx.x * 64;

    const char* wsW = ws + WSR_OFF;
    const char* wsF = ws + WSF_OFF;
    const float* recs = (const float*)(ws + REC_OFF);

    // stage first layer's first weights while the conditioning MLP runs
    prefetch_lds(wsW, BM, 32768, w, lane);

    float zz0 = 0.f, zz1 = 0.f, ld = 0.f;
    if (tid < 64) {
        int s = sbase + tid;
        float za = z0g[2 * s], zb = z0g[2 * s + 1];
        float xa = xg[2 * s],  xb = xg[2 * s + 1];
        float sg = sgg[s];
        float t0 = n1b2[0], t1 = n1b2[1];
#pragma unroll
        for (int m = 0; m < 32; ++m) {
            float hm = fmaf(sg, n1w1[m], n1b1[m]);
            hm = hm / (1.f + __expf(-hm));
            t0 = fmaf(hm, n1w2[m], t0);
            t1 = fmaf(hm, n1w2[32 + m], t1);
        }
        float u0 = n2b2[0], u1 = n2b2[1];
#pragma unroll
        for (int m = 0; m < 32; ++m) {
            float hm = za * n2w1[4 * m] + zb * n2w1[4 * m + 1]
                     + xa * n2w1[4 * m + 2] + xb * n2w1[4 * m + 3] + n2b1[m];
            hm = hm / (1.f + __expf(-hm));
            u0 = fmaf(hm, n2w2[m], u0);
            u1 = fmaf(hm, n2w2[32 + m], u1);
        }
        zz0 = u0 + t0; zz1 = u1 + t1;
    }

    f32x4 h[2][4];

    for (int L = 0; L < 16; ++L) {
        const float* rec = recs + L * 40;
        float out0 = 0.f, ldp0 = 0.f;
        if (tid < 64) {
            rqs_knots(zz0, rec, out0, ldp0);
            out0sh[tid] = out0;
        }
        __syncthreads();

        // ---- h init (in registers, C-layout) + write relu(h) to A0 ----
        {
            float w0v[2], b0v[2];
#pragma unroll
            for (int ct = 0; ct < 2; ++ct) {
                int c = (w << 5) + (ct << 4) + tx;
                w0v[ct] = W0g[L * 256 + 2 * c];
                b0v[ct] = b0g[L * 128 + c];
            }
#pragma unroll
            for (int rt = 0; rt < 4; ++rt)
#pragma unroll
                for (int reg = 0; reg < 4; ++reg) {
                    float o0 = out0sh[(rt << 4) + (q << 2) + reg];
#pragma unroll
                    for (int ct = 0; ct < 2; ++ct)
                        h[ct][rt][reg] = fmaf(o0, w0v[ct], b0v[ct]);
                }
            write_A<1>(A0, h, w, q, tx);
        }
        __syncthreads();

        const float* bb = bresg + L * 4 * 128;
        res_stage<0, 1>(A0, A1, BM, bb + 0, h,
                        wsW + (L * 4 + 1) * 32768, BM, 32768, nullptr, nullptr, 0,
                        w, q, tx, lane);
        __syncthreads();
        res_stage<1, 1>(A1, A0, BM, bb + 128, h,
                        wsW + (L * 4 + 2) * 32768, BM, 32768, nullptr, nullptr, 0,
                        w, q, tx, lane);
        __syncthreads();
        res_stage<0, 1>(A0, A1, BM, bb + 256, h,
                        wsW + (L * 4 + 3) * 32768, BM, 32768,
                        wsF + L * 8192, BP, 8192,
                        w, q, tx, lane);
        __syncthreads();
        {
            int Ln = (L < 15) ? (L + 1) : 15;
            res_stage<1, 0>(A1, A0, BM, bb + 384, h,
                            wsW + (Ln * 4) * 32768, BM, 32768, nullptr, nullptr, 0,
                            w, q, tx, lane);
        }
        __syncthreads();

        // ---- projection: p1 = h @ Wfpad^T + bf  (wave w does row-tile w) ----
        {
            f32x4 zero = {0.f, 0.f, 0.f, 0.f};
            f32x4 pacc[2]; pacc[0] = zero; pacc[1] = zero;
#pragma unroll
            for (int kt = 0; kt < 4; ++kt) {
                int cc = ((kt << 2) + q) ^ tx7;
                s16x8 a = *(const s16x8*)(A0 + (((w << 4) + tx) << 8) + (cc << 4));
#pragma unroll
                for (int ct = 0; ct < 2; ++ct) {
                    s16x8 b = *(const s16x8*)(BP + (((ct << 4) + tx) << 8) + (cc << 4));
                    pacc[ct] = __builtin_amdgcn_mfma_f32_16x16x32_bf16(a, b, pacc[ct], 0, 0, 0);
                }
            }
#pragma unroll
            for (int ct = 0; ct < 2; ++ct) {
                int o = (ct << 4) + tx;
                float bias = (o < 23) ? bfg[L * 46 + 23 + o] : 0.f;
#pragma unroll
                for (int reg = 0; reg < 4; ++reg) {
                    int r = (w << 4) + (q << 2) + reg;
                    p1sh[r * P1_STRIDE + o] = pacc[ct][reg] + bias;
                }
            }
        }
        __syncthreads();

        // ---- dim-1 spline + LU/permute (folded matrix from prep) ----
        if (tid < 64) {
            float pp[24];
            const float4* pr = (const float4*)&p1sh[tid * P1_STRIDE];
#pragma unroll
            for (int i = 0; i < 6; ++i) {
                float4 v4 = pr[i];
                pp[4 * i] = v4.x; pp[4 * i + 1] = v4.y; pp[4 * i + 2] = v4.z; pp[4 * i + 3] = v4.w;
            }
            float out1, ldp1;
            rqs_inv(zz1, pp, out1, ldp1);
            ld += ldp0 + ldp1;
            float v0 = out0 - rec[31], v1 = out1 - rec[32];
            zz0 = fmaf(v0, rec[27], v1 * rec[28]);
            zz1 = fmaf(v0, rec[29], v1 * rec[30]);
        }
    }

    if (tid < 64) {
        int s = sbase + tid;
        float ldc = *(const float*)(ws + LDC_OFF);
        outg[2 * s] = zz0;
        outg[2 * s + 1] = zz1;
        outg[2 * NBATCH + s] = ld - ldc;
    }
}

extern "C" void kernel_launch(void* const* d_in, const int* in_sizes, int n_in,
                              void* d_out, int out_size, void* d_ws, size_t ws_size,
                              hipStream_t stream)
{
    const float* z0g  = (const float*)d_in[0];
    const float* xg   = (const float*)d_in[1];
    const float* sgg  = (const float*)d_in[2];
    const float* n1w1 = (const float*)d_in[3];
    const float* n1b1 = (const float*)d_in[4];
    const float* n1w2 = (const float*)d_in[5];
    const float* n1b2 = (const float*)d_in[6];
    const float* n2w1 = (const float*)d_in[7];
    const float* n2b1 = (const float*)d_in[8];
    const float* n2w2 = (const float*)d_in[9];
    const float* n2b2 = (const float*)d_in[10];
    const float* W0g  = (const float*)d_in[11];
    const float* b0g  = (const float*)d_in[12];
    const float* Wres = (const float*)d_in[13];
    const float* bres = (const float*)d_in[14];
    const float* Wfg  = (const float*)d_in[15];
    const float* bfg  = (const float*)d_in[16];
    const float* lul  = (const float*)d_in[17];
    const float* luu  = (const float*)d_in[18];
    const float* lud  = (const float*)d_in[19];
    const float* lub  = (const float*)d_in[20];
    const int*   perms= (const int*)d_in[21];
    float* outg = (float*)d_out;

    static int attr_done = 0;
    hipFuncSetAttribute((const void*)nsf_kernel,
                        hipFuncAttributeMaxDynamicSharedMemorySize, SMEM_BYTES);
    (void)attr_done;

    nsf_prep<<<1024, 256, 0, stream>>>(Wres, Wfg, bfg, lul, luu, lud, lub, perms, (char*)d_ws);
    nsf_kernel<<<4096, 256, SMEM_BYTES, stream>>>(z0g, xg, sgg,
                                                  n1w1, n1b1, n1w2, n1b2,
                                                  n2w1, n2b1, n2w2, n2b2,
                                                  W0g, b0g, bres, bfg,
                                                  (const char*)d_ws, outg);
}

// Round 3
// 1208.267 us; speedup vs baseline: 13.8363x; 1.3965x over previous
//
#include <hip/hip_runtime.h>
#include <math.h>

#define NBATCH 262144
#define INVSQH 0.08838834764831845f   // 1/sqrt(128)

typedef float f32x4 __attribute__((ext_vector_type(4)));
typedef short s16x8 __attribute__((ext_vector_type(8)));

// ---- workspace layout (bytes) ----
#define WSR_OFF 0                 // Wres bf16 swizzled, half-K split: 16L*4st*2half*16384
#define WSF_OFF 2097152           // Wf padded [32][128] bf16 swizzled full-K: 16 * 8192
#define WS0_OFF 2228224           // W0 col0 packed: 16*128 f32
#define WSB_OFF 2236416           // proj bias padded: 16*32 f32
#define REC_OFF 2238464           // 16 * 40 f32 (cw9 ch9 d9 lu4 lub2)
#define LDC_OFF 2241024           // 1 f32: sum log-diag

// ---- LDS layout (bytes) ----
#define A_OFF   0                 // act: 128 rows * 256 B (bf16, swizzled 16B chunks)
#define BM_OFF  32768             // 2 x 16384 rotating weight-half buffers
#define O0_OFF  65536             // 128 f32
#define P1_OFF  66048             // 128 * 28 f32 = 14336
#define P1S     28
#define SMEM_BYTES 80384          // <= 81920 -> 2 blocks/CU

__device__ __forceinline__ float softplusf(float x) {
    return (x > 15.f) ? x : log1pf(__expf(x));
}
__device__ __forceinline__ unsigned short f2bf(float x) {
    unsigned u = __float_as_uint(x);
    unsigned r = (u + 0x7FFFu + ((u >> 16) & 1u)) >> 16;   // RNE
    return (unsigned short)r;
}

__device__ __forceinline__ void rqs_solve(float y, float yc, float yk, float hk, float xk,
                                          float wk, float dk, float dk1,
                                          float& xout, float& ldout)
{
    float sk = hk / wk;
    float dy = yc - yk;
    float t2 = dk + dk1 - 2.f * sk;
    float av = dy * t2 + hk * (sk - dk);
    float bv = hk * dk - dy * t2;
    float cv = -sk * dy;
    float disc = fmaxf(bv * bv - 4.f * av * cv, 0.f);
    float theta = 2.f * cv / (-bv - sqrtf(disc));
    float xo = fmaf(theta, wk, xk);
    float om = 1.f - theta;
    float denom = fmaf(t2, theta * om, sk);
    float dnum = sk * sk * (dk1 * theta * theta + 2.f * sk * theta * om + dk * om * om);
    float ldf = __logf(dnum) - 2.f * __logf(denom);
    bool inside = (y >= -3.f) && (y <= 3.f);
    xout  = inside ? xo : y;
    ldout = inside ? -ldf : 0.f;
}

// full RQS inverse from raw params p[0..22] (dim-1, per-sample)
__device__ __forceinline__ void rqs_inv(float y, const float* __restrict__ p,
                                        float& xout, float& ldout)
{
    float uw[8], uh[8];
#pragma unroll
    for (int j = 0; j < 8; ++j) uw[j] = p[j] * INVSQH;
#pragma unroll
    for (int j = 0; j < 8; ++j) uh[j] = p[8 + j] * INVSQH;
    float mw = uw[0], mh = uh[0];
#pragma unroll
    for (int j = 1; j < 8; ++j) { mw = fmaxf(mw, uw[j]); mh = fmaxf(mh, uh[j]); }
    float ew[8], eh[8], sw = 0.f, sh = 0.f;
#pragma unroll
    for (int j = 0; j < 8; ++j) {
        ew[j] = __expf(uw[j] - mw); sw += ew[j];
        eh[j] = __expf(uh[j] - mh); sh += eh[j];
    }
    float isw = 0.992f / sw, ish = 0.992f / sh;
    float cw[9], ch[9];
    cw[0] = -3.f; ch[0] = -3.f;
    float aw = 0.f, ah = 0.f;
#pragma unroll
    for (int j = 0; j < 8; ++j) {
        aw += 0.001f + ew[j] * isw;
        ah += 0.001f + eh[j] * ish;
        cw[j + 1] = 6.f * aw - 3.f;
        ch[j + 1] = 6.f * ah - 3.f;
    }
    cw[8] = 3.f; ch[8] = 3.f;
    float d[9];
    d[0] = 1.f; d[8] = 1.f;
#pragma unroll
    for (int j = 0; j < 7; ++j) d[j + 1] = 0.001f + softplusf(p[16 + j]);

    float yc = fminf(fmaxf(y, -3.f), 3.f);
    float yk = ch[0], hk = ch[1] - ch[0], xk = cw[0], wk = cw[1] - cw[0];
    float dk = d[0], dk1 = d[1];
#pragma unroll
    for (int j = 1; j < 8; ++j) {
        bool cge = (yc >= ch[j]);
        yk  = cge ? ch[j] : yk;
        hk  = cge ? (ch[j + 1] - ch[j]) : hk;
        xk  = cge ? cw[j] : xk;
        wk  = cge ? (cw[j + 1] - cw[j]) : wk;
        dk  = cge ? d[j] : dk;
        dk1 = cge ? d[j + 1] : dk1;
    }
    rqs_solve(y, yc, yk, hk, xk, wk, dk, dk1, xout, ldout);
}

// RQS inverse from precomputed knots rec = {cw[9], ch[9], d[9]} (dim-0, per-layer const)
__device__ __forceinline__ void rqs_knots(float y, const float* __restrict__ rec,
                                          float& xout, float& ldout)
{
    const float* cw = rec;
    const float* ch = rec + 9;
    const float* dd = rec + 18;
    float yc = fminf(fmaxf(y, -3.f), 3.f);
    float yk = ch[0], hk = ch[1] - ch[0], xk = cw[0], wk = cw[1] - cw[0];
    float dk = dd[0], dk1 = dd[1];
#pragma unroll
    for (int j = 1; j < 8; ++j) {
        bool cge = (yc >= ch[j]);
        yk  = cge ? ch[j] : yk;
        hk  = cge ? (ch[j + 1] - ch[j]) : hk;
        xk  = cge ? cw[j] : xk;
        wk  = cge ? (cw[j + 1] - cw[j]) : wk;
        dk  = cge ? dd[j] : dk;
        dk1 = cge ? dd[j + 1] : dk1;
    }
    rqs_solve(y, yc, yk, hk, xk, wk, dk, dk1, xout, ldout);
}

// async global->LDS, 16B/lane; wave w stages its quarter of nbytes.
// LDS dest is wave-uniform base; HW scatters lane*16 (m104/m108 caveat respected).
__device__ __forceinline__ void prefetch_lds(const char* src, char* dst, int nbytes,
                                             int w, int lane)
{
    int slice = nbytes >> 2;
    const char* s = src + w * slice + lane * 16;
    char* d = dst + w * slice;
    for (int i = 0; i < slice; i += 1024)
        __builtin_amdgcn_global_load_lds(
            (const __attribute__((address_space(1))) unsigned int*)(s + i),
            (__attribute__((address_space(3))) unsigned int*)(d + i), 16, 0, 0);
}

// packed bf16x4 store of one D-tile fragment into act buffer.
// element (m, k'=n) at byte m*256 + ((k'>>3)^(m&7))*16 + (k'&7)*2; lane's 4 k' consecutive.
__device__ __forceinline__ void pack_store(char* A, int m, int tn2, int i, int q, int tx7, f32x4 v)
{
    unsigned d0 = (unsigned)f2bf(v[0]) | ((unsigned)f2bf(v[1]) << 16);
    unsigned d1 = (unsigned)f2bf(v[2]) | ((unsigned)f2bf(v[3]) << 16);
    int chunk = ((tn2 << 3) + (i << 1) + (q >> 1)) ^ tx7;
    *(uint2*)(A + (m << 8) + (chunk << 4) + ((q & 1) << 3)) = make_uint2(d0, d1);
}

// one 128x128x128 transposed MFMA stage: out^T[n][m] = sum_k W[n][k] act[m][k].
// Wave w: tn2=w>>1 (n-half), tm2=w&1 (m-half), 4x4 tiles of 16x16.
// Two K-phases: phase p reads weight half from bmP, prefetches next item into the other buf.
// Write phase: acc+bias (+h residual), optional relu, packed b64 in-place into A.
template <int HSTAGE, int RELUOUT>
__device__ __forceinline__ void res_stage(char* A, char* bm0, char* bm1,
                                          const char* pf1, const char* pf2, int pf2n,
                                          const float* biasrow, f32x4 h[4][4],
                                          int tn2, int tm2, int q, int tx, int w, int lane)
{
    const int tx7 = tx & 7;
    f32x4 acc[4][4];
#pragma unroll
    for (int i = 0; i < 4; ++i)
#pragma unroll
        for (int j = 0; j < 4; ++j) acc[i][j] = (f32x4){0.f, 0.f, 0.f, 0.f};

#pragma unroll
    for (int ph = 0; ph < 2; ++ph) {
        const char* bm = ph ? bm1 : bm0;
        if (ph == 0) prefetch_lds(pf1, bm1, 16384, w, lane);
        else         prefetch_lds(pf2, bm0, pf2n, w, lane);
#pragma unroll
        for (int kt = 0; kt < 2; ++kt) {
            int ktg = (ph << 1) + kt;
            int ccW = ((kt << 2) + q) ^ tx7;       // chunk within 128B half-row
            int ccA = ((ktg << 2) + q) ^ tx7;      // chunk within 256B act row
            s16x8 wf[4], af[4];
#pragma unroll
            for (int i = 0; i < 4; ++i)
                wf[i] = *(const s16x8*)(bm + ((tn2 * 64 + i * 16 + tx) << 7) + (ccW << 4));
#pragma unroll
            for (int j = 0; j < 4; ++j)
                af[j] = *(const s16x8*)(A + ((tm2 * 64 + j * 16 + tx) << 8) + (ccA << 4));
#pragma unroll
            for (int i = 0; i < 4; ++i)
#pragma unroll
                for (int j = 0; j < 4; ++j)
                    acc[i][j] = __builtin_amdgcn_mfma_f32_16x16x32_bf16(wf[i], af[j], acc[i][j], 0, 0, 0);
        }
        __syncthreads();    // phase barrier: also forces this phase's prefetch landed
    }

#pragma unroll
    for (int i = 0; i < 4; ++i) {
        float4 bv = *(const float4*)(biasrow + tn2 * 64 + i * 16 + (q << 2));
#pragma unroll
        for (int j = 0; j < 4; ++j) {
            f32x4 v = acc[i][j];
            v[0] += bv.x; v[1] += bv.y; v[2] += bv.z; v[3] += bv.w;
            if (HSTAGE) { h[i][j] += v; v = h[i][j]; }
            if (RELUOUT) {
                v[0] = fmaxf(v[0], 0.f); v[1] = fmaxf(v[1], 0.f);
                v[2] = fmaxf(v[2], 0.f); v[3] = fmaxf(v[3], 0.f);
            }
            pack_store(A, tm2 * 64 + j * 16 + tx, tn2, i, q, tx7, v);
        }
    }
    __syncthreads();
}

// ---------------- prep kernel ----------------
extern "C" __global__ void nsf_prep(const float* __restrict__ Wresg, const float* __restrict__ Wfg,
                                    const float* __restrict__ bfg, const float* __restrict__ W0g,
                                    const float* __restrict__ lulg, const float* __restrict__ luug,
                                    const float* __restrict__ ludg, const float* __restrict__ lubg,
                                    const int* __restrict__ permsg, char* __restrict__ ws)
{
    int t = blockIdx.x * blockDim.x + threadIdx.x;
    int stride = gridDim.x * blockDim.x;
    unsigned short* wr = (unsigned short*)(ws + WSR_OFF);
    unsigned short* wf = (unsigned short*)(ws + WSF_OFF);
    float* ws0 = (float*)(ws + WS0_OFF);
    float* wsb = (float*)(ws + WSB_OFF);

    // Wres: stage sidx = L*4 + blk*2 + sub; split K into halves of 64
    for (int e = t; e < 16 * 4 * 16384; e += stride) {
        int sidx = e >> 14;
        int rem = e & 16383;
        int o = rem >> 7, k = rem & 127;
        int half = k >> 6, kr = k & 63;
        wr[(sidx * 2 + half) * 8192 + o * 64 + (((kr >> 3) ^ (o & 7)) << 3) + (kr & 7)]
            = f2bf(Wresg[e]);
    }
    // Wf padded to 32 rows, full-K 256B rows
    for (int e = t; e < 16 * 32 * 128; e += stride) {
        int L = e >> 12;
        int rem = e & 4095;
        int o = rem >> 7, k = rem & 127;
        float x = (o < 23) ? Wfg[(L * 46 + 23 + o) * 128 + k] : 0.f;
        wf[L * 4096 + o * 128 + (((k >> 3) ^ (o & 7)) << 3) + (k & 7)] = f2bf(x);
    }
    // W0 column 0 packed; padded proj bias
    for (int e = t; e < 16 * 128; e += stride)
        ws0[e] = W0g[2 * e];
    for (int e = t; e < 16 * 32; e += stride) {
        int L = e >> 5, o = e & 31;
        wsb[e] = (o < 23) ? bfg[L * 46 + 23 + o] : 0.f;
    }
    // per-layer: dim0 spline knots + folded LU/perm
    if (t < 16) {
        int L = t;
        float* rec = (float*)(ws + REC_OFF) + L * 40;
        const float* p = bfg + L * 46;
        for (int half = 0; half < 2; ++half) {
            float u[8], m = -1e30f;
            for (int j = 0; j < 8; ++j) { u[j] = p[half * 8 + j] * INVSQH; m = fmaxf(m, u[j]); }
            float e[8], s = 0.f;
            for (int j = 0; j < 8; ++j) { e[j] = expf(u[j] - m); s += e[j]; }
            float cum = 0.f;
            rec[half * 9 + 0] = -3.f;
            for (int j = 0; j < 8; ++j) {
                cum += 0.001f + 0.992f * e[j] / s;
                rec[half * 9 + 1 + j] = 6.f * cum - 3.f;
            }
            rec[half * 9 + 8] = 3.f;
        }
        rec[18] = 1.f; rec[26] = 1.f;
        for (int j = 0; j < 7; ++j) {
            float x = p[16 + j];
            rec[19 + j] = 0.001f + ((x > 15.f) ? x : log1pf(expf(x)));
        }
        float x0 = ludg[2 * L], x1 = ludg[2 * L + 1];
        float dg0 = 0.001f + ((x0 > 15.f) ? x0 : log1pf(expf(x0)));
        float dg1 = 0.001f + ((x1 > 15.f) ? x1 : log1pf(expf(x1)));
        float ll = lulg[L], uu = luug[L];
        float det = dg0 * dg1;
        float c00 = (ll * uu + dg1) / det, c01 = -uu / det;
        float c10 = -ll / dg1, c11 = 1.f / dg1;
        int pa = permsg[2 * L], pb = permsg[2 * L + 1];
        rec[27] = pa ? c10 : c00; rec[28] = pa ? c11 : c01;
        rec[29] = pb ? c10 : c00; rec[30] = pb ? c11 : c01;
        rec[31] = lubg[2 * L];    rec[32] = lubg[2 * L + 1];
    }
    if (t == 16) {
        float s = 0.f;
        for (int L = 0; L < 16; ++L) {
            float x0 = ludg[2 * L], x1 = ludg[2 * L + 1];
            float dg0 = 0.001f + ((x0 > 15.f) ? x0 : log1pf(expf(x0)));
            float dg1 = 0.001f + ((x1 > 15.f) ? x1 : log1pf(expf(x1)));
            s += logf(dg0) + logf(dg1);
        }
        *(float*)(ws + LDC_OFF) = s;
    }
}

// ---------------- main fused kernel ----------------
extern "C" __global__ __launch_bounds__(256, 2)
void nsf_kernel(const float* __restrict__ z0g, const float* __restrict__ xg,
                const float* __restrict__ sgg,
                const float* __restrict__ n1w1, const float* __restrict__ n1b1,
                const float* __restrict__ n1w2, const float* __restrict__ n1b2,
                const float* __restrict__ n2w1, const float* __restrict__ n2b1,
                const float* __restrict__ n2w2, const float* __restrict__ n2b2,
                const float* __restrict__ b0g,  const float* __restrict__ bresg,
                const char* __restrict__ ws, float* __restrict__ outg)
{
    extern __shared__ char smem[];
    char* A  = smem + A_OFF;
    char* BM = smem + BM_OFF;
    float* out0sh = (float*)(smem + O0_OFF);
    float* p1f = (float*)(smem + P1_OFF);

    const int tid = threadIdx.x;
    const int lane = tid & 63, w = tid >> 6;
    const int q = lane >> 4, tx = lane & 15, tx7 = tx & 7;
    const int tn2 = w >> 1, tm2 = w & 1;
    const int sbase = blockIdx.x * 128;

    const char* wsW = ws + WSR_OFF;
    const char* wsF = ws + WSF_OFF;
    const float* ws0 = (const float*)(ws + WS0_OFF);
    const float* wsb = (const float*)(ws + WSB_OFF);
    const float* recs = (const float*)(ws + REC_OFF);

    // stage layer-0 stage-0 k-half-0 while conditioning MLP runs (item 0 -> buf 0)
    prefetch_lds(wsW, BM, 16384, w, lane);

    float zz0 = 0.f, zz1 = 0.f, ld = 0.f;
    if (tid < 128) {
        int s = sbase + tid;
        float za = z0g[2 * s], zb = z0g[2 * s + 1];
        float xa = xg[2 * s],  xb = xg[2 * s + 1];
        float sg = sgg[s];
        float t0 = n1b2[0], t1 = n1b2[1];
#pragma unroll
        for (int m = 0; m < 32; ++m) {
            float hm = fmaf(sg, n1w1[m], n1b1[m]);
            hm = hm / (1.f + __expf(-hm));
            t0 = fmaf(hm, n1w2[m], t0);
            t1 = fmaf(hm, n1w2[32 + m], t1);
        }
        float u0 = n2b2[0], u1 = n2b2[1];
#pragma unroll
        for (int m = 0; m < 32; ++m) {
            float hm = za * n2w1[4 * m] + zb * n2w1[4 * m + 1]
                     + xa * n2w1[4 * m + 2] + xb * n2w1[4 * m + 3] + n2b1[m];
            hm = hm / (1.f + __expf(-hm));
            u0 = fmaf(hm, n2w2[m], u0);
            u1 = fmaf(hm, n2w2[32 + m], u1);
        }
        zz0 = u0 + t0; zz1 = u1 + t1;
    }

    f32x4 h[4][4];
    int pbuf = 0;   // parity of the buffer holding the current layer's first item

    for (int L = 0; L < 16; ++L) {
        const float* rec = recs + L * 40;
        float out0 = 0.f, ldp0 = 0.f;
        if (tid < 128) {
            rqs_knots(zz0, rec, out0, ldp0);
            out0sh[tid] = out0;
        }
        __syncthreads();                                   // B0

        // ---- h init in registers + packed relu write into A ----
        {
#pragma unroll
            for (int i = 0; i < 4; ++i) {
                int n0 = tn2 * 64 + i * 16 + (q << 2);
                float4 w0v = *(const float4*)(ws0 + L * 128 + n0);
                float4 b0v = *(const float4*)(b0g + L * 128 + n0);
#pragma unroll
                for (int j = 0; j < 4; ++j) {
                    int m = tm2 * 64 + j * 16 + tx;
                    float o0 = out0sh[m];
                    f32x4 v;
                    v[0] = fmaf(o0, w0v.x, b0v.x);
                    v[1] = fmaf(o0, w0v.y, b0v.y);
                    v[2] = fmaf(o0, w0v.z, b0v.z);
                    v[3] = fmaf(o0, w0v.w, b0v.w);
                    h[i][j] = v;
                    v[0] = fmaxf(v[0], 0.f); v[1] = fmaxf(v[1], 0.f);
                    v[2] = fmaxf(v[2], 0.f); v[3] = fmaxf(v[3], 0.f);
                    pack_store(A, m, tn2, i, q, tx7, v);
                }
            }
        }
        __syncthreads();                                   // B1

        char* b0p = BM + pbuf * 16384;
        char* b1p = BM + (pbuf ^ 1) * 16384;
        const char* sw = wsW + L * 4 * 32768;
        const float* bb = bresg + L * 4 * 128;

        res_stage<0, 1>(A, b0p, b1p, sw + 16384,  sw + 32768,  16384, bb + 0,   h, tn2, tm2, q, tx, w, lane);
        res_stage<1, 1>(A, b0p, b1p, sw + 49152,  sw + 65536,  16384, bb + 128, h, tn2, tm2, q, tx, w, lane);
        res_stage<0, 1>(A, b0p, b1p, sw + 81920,  sw + 98304,  16384, bb + 256, h, tn2, tm2, q, tx, w, lane);
        res_stage<1, 0>(A, b0p, b1p, sw + 114688, wsF + L * 8192, 8192, bb + 384, h, tn2, tm2, q, tx, w, lane);

        // ---- projection: p1^T[o][m], Wf in b0p (8 KB), act in A ----
        {
            if (L < 15) prefetch_lds(wsW + (L + 1) * 4 * 32768, b1p, 16384, w, lane);
            f32x4 pacc[2][2];
#pragma unroll
            for (int ct = 0; ct < 2; ++ct)
#pragma unroll
                for (int jm = 0; jm < 2; ++jm) pacc[ct][jm] = (f32x4){0.f, 0.f, 0.f, 0.f};
#pragma unroll
            for (int ktg = 0; ktg < 4; ++ktg) {
                int ccA = ((ktg << 2) + q) ^ tx7;
                s16x8 wfr[2], afr[2];
#pragma unroll
                for (int ct = 0; ct < 2; ++ct)
                    wfr[ct] = *(const s16x8*)(b0p + ((ct * 16 + tx) << 8) + (ccA << 4));
#pragma unroll
                for (int jm = 0; jm < 2; ++jm)
                    afr[jm] = *(const s16x8*)(A + (((w << 5) + jm * 16 + tx) << 8) + (ccA << 4));
#pragma unroll
                for (int ct = 0; ct < 2; ++ct)
#pragma unroll
                    for (int jm = 0; jm < 2; ++jm)
                        pacc[ct][jm] = __builtin_amdgcn_mfma_f32_16x16x32_bf16(wfr[ct], afr[jm], pacc[ct][jm], 0, 0, 0);
            }
#pragma unroll
            for (int ct = 0; ct < 2; ++ct) {
                if (ct == 0 || q < 2) {
                    float4 bias = *(const float4*)(wsb + L * 32 + ct * 16 + (q << 2));
#pragma unroll
                    for (int jm = 0; jm < 2; ++jm) {
                        int m = (w << 5) + jm * 16 + tx;
                        float4 o;
                        o.x = pacc[ct][jm][0] + bias.x;
                        o.y = pacc[ct][jm][1] + bias.y;
                        o.z = pacc[ct][jm][2] + bias.z;
                        o.w = pacc[ct][jm][3] + bias.w;
                        *(float4*)(p1f + m * P1S + ct * 16 + (q << 2)) = o;
                    }
                }
            }
        }
        __syncthreads();                                   // proj-end

        // ---- dim-1 spline + folded LU/permute ----
        if (tid < 128) {
            float pp[24];
            const float4* pr = (const float4*)(p1f + tid * P1S);
#pragma unroll
            for (int i = 0; i < 6; ++i) {
                float4 v4 = pr[i];
                pp[4 * i] = v4.x; pp[4 * i + 1] = v4.y; pp[4 * i + 2] = v4.z; pp[4 * i + 3] = v4.w;
            }
            float out1, ldp1;
            rqs_inv(zz1, pp, out1, ldp1);
            ld += ldp0 + ldp1;
            float v0 = out0 - rec[31], v1 = out1 - rec[32];
            zz0 = fmaf(v0, rec[27], v1 * rec[28]);
            zz1 = fmaf(v0, rec[29], v1 * rec[30]);
        }
        pbuf ^= 1;   // 9 weight items per layer -> parity flips
    }

    if (tid < 128) {
        int s = sbase + tid;
        float ldc = *(const float*)(ws + LDC_OFF);
        outg[2 * s] = zz0;
        outg[2 * s + 1] = zz1;
        outg[2 * NBATCH + s] = ld - ldc;
    }
}

extern "C" void kernel_launch(void* const* d_in, const int* in_sizes, int n_in,
                              void* d_out, int out_size, void* d_ws, size_t ws_size,
                              hipStream_t stream)
{
    const float* z0g  = (const float*)d_in[0];
    const float* xg   = (const float*)d_in[1];
    const float* sgg  = (const float*)d_in[2];
    const float* n1w1 = (const float*)d_in[3];
    const float* n1b1 = (const float*)d_in[4];
    const float* n1w2 = (const float*)d_in[5];
    const float* n1b2 = (const float*)d_in[6];
    const float* n2w1 = (const float*)d_in[7];
    const float* n2b1 = (const float*)d_in[8];
    const float* n2w2 = (const float*)d_in[9];
    const float* n2b2 = (const float*)d_in[10];
    const float* W0g  = (const float*)d_in[11];
    const float* b0g  = (const float*)d_in[12];
    const float* Wres = (const float*)d_in[13];
    const float* bres = (const float*)d_in[14];
    const float* Wfg  = (const float*)d_in[15];
    const float* bfg  = (const float*)d_in[16];
    const float* lul  = (const float*)d_in[17];
    const float* luu  = (const float*)d_in[18];
    const float* lud  = (const float*)d_in[19];
    const float* lub  = (const float*)d_in[20];
    const int*   perms= (const int*)d_in[21];
    float* outg = (float*)d_out;

    hipFuncSetAttribute((const void*)nsf_kernel,
                        hipFuncAttributeMaxDynamicSharedMemorySize, SMEM_BYTES);

    nsf_prep<<<1024, 256, 0, stream>>>(Wres, Wfg, bfg, W0g, lul, luu, lud, lub, perms, (char*)d_ws);
    nsf_kernel<<<NBATCH / 128, 256, SMEM_BYTES, stream>>>(z0g, xg, sgg,
                                                          n1w1, n1b1, n1w2, n1b2,
                                                          n2w1, n2b1, n2w2, n2b2,
                                                          b0g, bres,
                                                          (const char*)d_ws, outg);
}